// Round 2
// baseline (93.546 us; speedup 1.0000x reference)
//
#include <hip/hip_runtime.h>

#define NB 16
#define BATCH 8
#define PLANE (512*512)           // 262144 px per channel plane
#define FBINS 512                 // fine histogram resolution
#define CHUNKS 128
#define CTHREADS 512              // count kernel: 8 waves/block
#define PX_PER_BLOCK (PLANE / CHUNKS)          // 2048 = CTHREADS*4
#define SLICES 8                               // fine-bin slices in combine
#define FPB (FBINS / SLICES)                   // 64 fine bins per combine block
#define NCOMBINE (SLICES * 24)                 // 192 combine blocks

#if __has_builtin(__builtin_amdgcn_exp2f)
__device__ __forceinline__ float exp2_fast(float x) { return __builtin_amdgcn_exp2f(x); }
#else
__device__ __forceinline__ float exp2_fast(float x) { return __expf(x * 0.69314718056f); }
#endif

// weight = exp(-128*(x - i/15)^2) = exp2( -(128*log2(e)/225) * (15x - i)^2 )
#define NEG_C2 (-0.8207331788f)

__device__ __forceinline__ int qbin(float x) {
    int f = (int)(x * (float)FBINS);
    return f > (FBINS - 1) ? (FBINS - 1) : f;
}

// ---------------------------------------------------------------------------
// 1) masked fine histogram. LDS: 3 arrays of FBINS u32, each word packs two
//    channels (lo16 = ch 2k, hi16 = ch 2k+1). Max count/half = 2048 -> no carry.
//    512 threads = 8 waves/block, 4 blocks/CU -> 32 waves/CU (100% occ).
//    Channel order h in [0,6): p0,p1,p2,t0,t1,t2.
//    UNCHANGED except: block (0,0) zeroes the combine-done counter (the
//    workspace is re-poisoned each iteration, so it must be zeroed in-stream;
//    kernel-boundary ordering makes the store visible to combine_kernel).
// ---------------------------------------------------------------------------
__global__ __launch_bounds__(CTHREADS, 8)
void count_kernel(const float* __restrict__ pred,
                  const float* __restrict__ tgt,
                  unsigned int* __restrict__ partial,
                  unsigned int* __restrict__ ctr)
{
    const int chunk = blockIdx.x;
    const int b     = blockIdx.y;
    const int tid   = threadIdx.x;

    if (chunk == 0 && b == 0 && tid == 0) ctr[0] = 0u;

    __shared__ unsigned int cnt[3 * FBINS];   // 6 KB
    #pragma unroll
    for (int k = 0; k < 3 * FBINS / CTHREADS; ++k)
        cnt[tid + k * CTHREADS] = 0u;
    __syncthreads();

    const float* pb = pred + (size_t)b * 3 * PLANE;
    const float* tb = tgt  + (size_t)b * 3 * PLANE;
    const int p = chunk * PX_PER_BLOCK + tid * 4;

    const float4 P0 = *(const float4*)(pb + p);
    const float4 P1 = *(const float4*)(pb + PLANE + p);
    const float4 P2 = *(const float4*)(pb + 2 * PLANE + p);
    const float4 T0 = *(const float4*)(tb + p);
    const float4 T1 = *(const float4*)(tb + PLANE + p);
    const float4 T2 = *(const float4*)(tb + 2 * PLANE + p);

    const float p0a[4] = {P0.x, P0.y, P0.z, P0.w};
    const float p1a[4] = {P1.x, P1.y, P1.z, P1.w};
    const float p2a[4] = {P2.x, P2.y, P2.z, P2.w};
    const float t0a[4] = {T0.x, T0.y, T0.z, T0.w};
    const float t1a[4] = {T1.x, T1.y, T1.z, T1.w};
    const float t2a[4] = {T2.x, T2.y, T2.z, T2.w};

    #pragma unroll
    for (int j = 0; j < 4; ++j) {
        const bool m = (t0a[j] + t1a[j] + t2a[j]) * (1.0f / 3.0f) > 0.4f;
        if (m) {
            atomicAdd(&cnt[           qbin(p0a[j])], 1u);       // h=0 lo
            atomicAdd(&cnt[           qbin(p1a[j])], 65536u);   // h=1 hi
            atomicAdd(&cnt[FBINS    + qbin(p2a[j])], 1u);       // h=2 lo
            atomicAdd(&cnt[FBINS    + qbin(t0a[j])], 65536u);   // h=3 hi
            atomicAdd(&cnt[2*FBINS  + qbin(t1a[j])], 1u);       // h=4 lo
            atomicAdd(&cnt[2*FBINS  + qbin(t2a[j])], 65536u);   // h=5 hi
        }
    }
    __syncthreads();

    // flush 1536 words -> partial[h2][b][chunk][f]
    #pragma unroll
    for (int k = 0; k < 3 * FBINS / CTHREADS; ++k) {
        const int w  = tid + k * CTHREADS;
        const int h2 = w >> 9;
        const int f  = w & (FBINS - 1);
        partial[(((size_t)h2 * BATCH + b) * CHUNKS + chunk) * FBINS + f] = cnt[w];
    }
}

// ---------------------------------------------------------------------------
// 2) reduce partials over chunks + Gaussian conv -> out2[slice][hb][NB],
//    then the LAST block to finish (device-scope counter) runs the finalize
//    phase in-place: sum slices, normalize, L1, mean -> out[0].
//    Phases 1/2 verbatim from the verified r1 kernel.
// ---------------------------------------------------------------------------
__global__ __launch_bounds__(512)
void combine_kernel(const unsigned int* __restrict__ partial,
                    float* __restrict__ out2 /* [SLICES][48][NB] */,
                    unsigned int* __restrict__ ctr,
                    float* __restrict__ out)
{
    const int slice = blockIdx.x;      // 0..SLICES-1
    const int pb    = blockIdx.y;      // h2*BATCH + b, 0..23
    const int tid   = threadIdx.x;     // 0..511

    const int f_loc = tid & (FPB - 1);     // 0..63
    const int q     = tid >> 6;            // 0..7  (16 chunks each)
    const int f     = slice * FPB + f_loc;

    const unsigned int* base =
        partial + ((size_t)pb * CHUNKS + q * 16) * FBINS + f;
    unsigned int slo = 0u, shi = 0u;
    #pragma unroll
    for (int c = 0; c < 16; ++c) {
        const unsigned int v = base[(size_t)c * FBINS];
        slo += v & 0xFFFFu;                // sum <= 16*2048 = 32768: exact
        shi += v >> 16;
    }

    __shared__ float red_lo[8][FPB];       // 2 KB
    __shared__ float red_hi[8][FPB];       // 2 KB
    red_lo[q][f_loc] = (float)slo;
    red_hi[q][f_loc] = (float)shi;
    __syncthreads();

    // phase 2: 512 threads: half = t>>8 (lo/hi channel), fg = (t>>4)&15
    // (group of 4 fine bins), i = t&15 (coarse bin).
    const int i    = tid & 15;
    const int fg   = (tid >> 4) & 15;
    const int half = tid >> 8;

    float val = 0.0f;
    #pragma unroll
    for (int k = 0; k < 4; ++k) {
        const int fl = fg * 4 + k;
        float c;
        if (half == 0)
            c = red_lo[0][fl] + red_lo[1][fl] + red_lo[2][fl] + red_lo[3][fl]
              + red_lo[4][fl] + red_lo[5][fl] + red_lo[6][fl] + red_lo[7][fl];
        else
            c = red_hi[0][fl] + red_hi[1][fl] + red_hi[2][fl] + red_hi[3][fl]
              + red_hi[4][fl] + red_hi[5][fl] + red_hi[6][fl] + red_hi[7][fl];
        const float y = ((float)(slice * FPB + fl) + 0.5f) * (15.0f / (float)FBINS);
        const float u = y - (float)i;
        val += c * exp2_fast(u * u * NEG_C2);
    }

    // wave w covers fg in {4w..4w+3} (mod 16): fold fg-bits 0,1 (lane bits 4,5)
    val += __shfl_xor(val, 16, 64);
    val += __shfl_xor(val, 32, 64);
    // now every lane holds its wave's partial sum for coarse bin i

    __shared__ float acc[8][NB];           // [wave][i]
    if ((tid & 63) < 16) acc[tid >> 6][i] = val;
    __syncthreads();

    if (tid < 32) {
        const int hf = tid >> 4;           // 0=lo,1=hi
        const int ii = tid & 15;
        const int w0 = hf * 4;             // waves 0-3: lo, 4-7: hi
        const float v = acc[w0][ii] + acc[w0+1][ii] + acc[w0+2][ii] + acc[w0+3][ii];
        const int h2 = pb >> 3;
        const int b  = pb & 7;
        const int h  = h2 * 2 + hf;        // lo16 = even h, hi16 = odd h
        out2[((size_t)slice * 48 + h * BATCH + b) * NB + ii] = v;
    }
    __syncthreads();                       // out2 stores issued block-wide

    // ---- last-block-done gate (device scope) ----
    __shared__ unsigned int lastFlag;
    if (tid == 0) {
        __threadfence();                   // release our out2 stores
        lastFlag = (atomicAdd(ctr, 1u) == NCOMBINE - 1) ? 1u : 0u;
    }
    __syncthreads();
    if (lastFlag == 0u) return;
    __threadfence();                       // acquire all blocks' out2 stores

    // ---- fused finalize: sum slices, normalize, L1, mean ----
    __shared__ float H[48 * NB];           // [h*BATCH+b][i]
    for (int e = tid; e < 48 * NB; e += 512) {
        float v = 0.0f;
        #pragma unroll
        for (int s = 0; s < SLICES; ++s)
            v += out2[(size_t)s * 48 * NB + e];
        H[e] = v;
    }
    __syncthreads();

    if (tid < 384) {
        const int t   = tid;
        const int b   = t / 48;
        const int rem = t % 48;
        const int c   = rem / NB;
        const int ii  = rem % NB;

        const float* hp = H + ((c    ) * BATCH + b) * NB;  // pred
        const float* ht = H + ((c + 3) * BATCH + b) * NB;  // target
        float sp = 0.0f, st = 0.0f;
        #pragma unroll
        for (int k = 0; k < NB; ++k) { sp += hp[k]; st += ht[k]; }

        float v2 = fabsf(hp[ii] / (sp + 1e-7f) - ht[ii] / (st + 1e-7f));

        #pragma unroll
        for (int off = 32; off > 0; off >>= 1)
            v2 += __shfl_down(v2, off, 64);

        __shared__ float r[6];
        const int lane = t & 63, wv = t >> 6;
        if (lane == 0) r[wv] = v2;
        // waves 0-5 all inside tid<384: barrier-free handoff via LDS is not
        // safe across waves -> use s_barrier through __syncthreads below.
        __syncthreads();
        if (t == 0)
            out[0] = (r[0] + r[1] + r[2] + r[3] + r[4] + r[5]) * (1.0f / 384.0f);
    }
}

extern "C" void kernel_launch(void* const* d_in, const int* in_sizes, int n_in,
                              void* d_out, int out_size, void* d_ws, size_t ws_size,
                              hipStream_t stream)
{
    const float* pred = (const float*)d_in[0];
    const float* tgt  = (const float*)d_in[1];

    unsigned int* partial = (unsigned int*)d_ws;  // 3*8*128*512*4 = 6.29 MB
    float* out2 = (float*)((char*)d_ws + (size_t)3 * BATCH * CHUNKS * FBINS * 4);
    unsigned int* ctr = (unsigned int*)((char*)out2 + (size_t)SLICES * 48 * NB * 4);

    count_kernel<<<dim3(CHUNKS, BATCH), CTHREADS, 0, stream>>>(pred, tgt, partial, ctr);
    combine_kernel<<<dim3(SLICES, 24), 512, 0, stream>>>(partial, out2, ctr, (float*)d_out);
}

// Round 3
// 89.138 us; speedup vs baseline: 1.0494x; 1.0494x over previous
//
#include <hip/hip_runtime.h>

#define NB 16
#define BATCH 8
#define PLANE (512*512)           // 262144 px per channel plane
#define FBINS 512                 // fine histogram resolution
#define CHUNKS 128
#define CTHREADS 512              // count kernel: 8 waves/block
#define PX_PER_BLOCK (PLANE / CHUNKS)          // 2048 = CTHREADS*4
#define SLICES 8                               // fine-bin slices in combine
#define FPB (FBINS / SLICES)                   // 64 fine bins per combine block

#if __has_builtin(__builtin_amdgcn_exp2f)
__device__ __forceinline__ float exp2_fast(float x) { return __builtin_amdgcn_exp2f(x); }
#else
__device__ __forceinline__ float exp2_fast(float x) { return __expf(x * 0.69314718056f); }
#endif

// weight = exp(-128*(x - i/15)^2) = exp2( -(128*log2(e)/225) * (15x - i)^2 )
#define NEG_C2 (-0.8207331788f)

__device__ __forceinline__ int qbin(float x) {
    int f = (int)(x * (float)FBINS);
    return f > (FBINS - 1) ? (FBINS - 1) : f;
}

// ---------------------------------------------------------------------------
// 1) masked fine histogram. LDS: 3 arrays of FBINS u32, each word packs two
//    channels (lo16 = ch 2k, hi16 = ch 2k+1). Max count/half = 2048 -> no carry.
//    512 threads = 8 waves/block, 4 blocks/CU -> 32 waves/CU (100% occ).
//    Channel order h in [0,6): p0,p1,p2,t0,t1,t2.
// ---------------------------------------------------------------------------
__global__ __launch_bounds__(CTHREADS, 8)
void count_kernel(const float* __restrict__ pred,
                  const float* __restrict__ tgt,
                  unsigned int* __restrict__ partial
                  /* [3][BATCH][CHUNKS][FBINS] */)
{
    const int chunk = blockIdx.x;
    const int b     = blockIdx.y;
    const int tid   = threadIdx.x;

    __shared__ unsigned int cnt[3 * FBINS];   // 6 KB
    #pragma unroll
    for (int k = 0; k < 3 * FBINS / CTHREADS; ++k)
        cnt[tid + k * CTHREADS] = 0u;
    __syncthreads();

    const float* pb = pred + (size_t)b * 3 * PLANE;
    const float* tb = tgt  + (size_t)b * 3 * PLANE;
    const int p = chunk * PX_PER_BLOCK + tid * 4;

    const float4 P0 = *(const float4*)(pb + p);
    const float4 P1 = *(const float4*)(pb + PLANE + p);
    const float4 P2 = *(const float4*)(pb + 2 * PLANE + p);
    const float4 T0 = *(const float4*)(tb + p);
    const float4 T1 = *(const float4*)(tb + PLANE + p);
    const float4 T2 = *(const float4*)(tb + 2 * PLANE + p);

    const float p0a[4] = {P0.x, P0.y, P0.z, P0.w};
    const float p1a[4] = {P1.x, P1.y, P1.z, P1.w};
    const float p2a[4] = {P2.x, P2.y, P2.z, P2.w};
    const float t0a[4] = {T0.x, T0.y, T0.z, T0.w};
    const float t1a[4] = {T1.x, T1.y, T1.z, T1.w};
    const float t2a[4] = {T2.x, T2.y, T2.z, T2.w};

    #pragma unroll
    for (int j = 0; j < 4; ++j) {
        const bool m = (t0a[j] + t1a[j] + t2a[j]) * (1.0f / 3.0f) > 0.4f;
        if (m) {
            atomicAdd(&cnt[           qbin(p0a[j])], 1u);       // h=0 lo
            atomicAdd(&cnt[           qbin(p1a[j])], 65536u);   // h=1 hi
            atomicAdd(&cnt[FBINS    + qbin(p2a[j])], 1u);       // h=2 lo
            atomicAdd(&cnt[FBINS    + qbin(t0a[j])], 65536u);   // h=3 hi
            atomicAdd(&cnt[2*FBINS  + qbin(t1a[j])], 1u);       // h=4 lo
            atomicAdd(&cnt[2*FBINS  + qbin(t2a[j])], 65536u);   // h=5 hi
        }
    }
    __syncthreads();

    // flush 1536 words -> partial[h2][b][chunk][f]
    #pragma unroll
    for (int k = 0; k < 3 * FBINS / CTHREADS; ++k) {
        const int w  = tid + k * CTHREADS;
        const int h2 = w >> 9;
        const int f  = w & (FBINS - 1);
        partial[(((size_t)h2 * BATCH + b) * CHUNKS + chunk) * FBINS + f] = cnt[w];
    }
}

// ---------------------------------------------------------------------------
// 2) reduce partials over chunks + Gaussian conv -> out2[slice][hb][NB]
//    One block per (slice, h2*BATCH+b) handles BOTH 16-bit halves
//    -> partial read once (6.3 MB), 192 blocks x 512 threads.
// ---------------------------------------------------------------------------
__global__ __launch_bounds__(512)
void combine_kernel(const unsigned int* __restrict__ partial,
                    float* __restrict__ out2 /* [SLICES][48][NB] */)
{
    const int slice = blockIdx.x;      // 0..SLICES-1
    const int pb    = blockIdx.y;      // h2*BATCH + b, 0..23
    const int tid   = threadIdx.x;     // 0..511

    const int f_loc = tid & (FPB - 1);     // 0..63
    const int q     = tid >> 6;            // 0..7  (16 chunks each)
    const int f     = slice * FPB + f_loc;

    const unsigned int* base =
        partial + ((size_t)pb * CHUNKS + q * 16) * FBINS + f;
    unsigned int slo = 0u, shi = 0u;
    #pragma unroll
    for (int c = 0; c < 16; ++c) {
        const unsigned int v = base[(size_t)c * FBINS];
        slo += v & 0xFFFFu;                // sum <= 16*2048 = 32768: exact
        shi += v >> 16;
    }

    __shared__ float red_lo[8][FPB];       // 2 KB
    __shared__ float red_hi[8][FPB];       // 2 KB
    red_lo[q][f_loc] = (float)slo;
    red_hi[q][f_loc] = (float)shi;
    __syncthreads();

    // phase 2: 512 threads: half = t>>8 (lo/hi channel), fg = (t>>4)&15
    // (group of 4 fine bins), i = t&15 (coarse bin).
    const int i    = tid & 15;
    const int fg   = (tid >> 4) & 15;
    const int half = tid >> 8;

    float val = 0.0f;
    #pragma unroll
    for (int k = 0; k < 4; ++k) {
        const int fl = fg * 4 + k;
        float c;
        if (half == 0)
            c = red_lo[0][fl] + red_lo[1][fl] + red_lo[2][fl] + red_lo[3][fl]
              + red_lo[4][fl] + red_lo[5][fl] + red_lo[6][fl] + red_lo[7][fl];
        else
            c = red_hi[0][fl] + red_hi[1][fl] + red_hi[2][fl] + red_hi[3][fl]
              + red_hi[4][fl] + red_hi[5][fl] + red_hi[6][fl] + red_hi[7][fl];
        const float y = ((float)(slice * FPB + fl) + 0.5f) * (15.0f / (float)FBINS);
        const float u = y - (float)i;
        val += c * exp2_fast(u * u * NEG_C2);
    }

    // wave w covers fg in {4w..4w+3} (mod 16): fold fg-bits 0,1 (lane bits 4,5)
    val += __shfl_xor(val, 16, 64);
    val += __shfl_xor(val, 32, 64);
    // now every lane holds its wave's partial sum for coarse bin i

    __shared__ float acc[8][NB];           // [wave][i]
    if ((tid & 63) < 16) acc[tid >> 6][i] = val;
    __syncthreads();

    if (tid < 32) {
        const int hf = tid >> 4;           // 0=lo,1=hi
        const int ii = tid & 15;
        const int w0 = hf * 4;             // waves 0-3: lo, 4-7: hi
        const float v = acc[w0][ii] + acc[w0+1][ii] + acc[w0+2][ii] + acc[w0+3][ii];
        const int h2 = pb >> 3;
        const int b  = pb & 7;
        const int h  = h2 * 2 + hf;        // lo16 = even h, hi16 = odd h
        out2[((size_t)slice * 48 + h * BATCH + b) * NB + ii] = v;
    }
}

// ---------------------------------------------------------------------------
// 3) sum slices, normalize, L1, mean
// ---------------------------------------------------------------------------
__global__ void finalize_kernel(const float* __restrict__ out2,
                                float* __restrict__ out)
{
    const int t = threadIdx.x;      // 384 threads
    __shared__ float H[48 * NB];    // [h*BATCH+b][i]

    for (int e = t; e < 48 * NB; e += 384) {
        float v = 0.0f;
        #pragma unroll
        for (int s = 0; s < SLICES; ++s)
            v += out2[(size_t)s * 48 * NB + e];
        H[e] = v;
    }
    __syncthreads();

    const int b   = t / 48;
    const int rem = t % 48;
    const int c   = rem / NB;
    const int i   = rem % NB;

    const float* hp = H + ((c    ) * BATCH + b) * NB;  // pred
    const float* ht = H + ((c + 3) * BATCH + b) * NB;  // target
    float sp = 0.0f, st = 0.0f;
    #pragma unroll
    for (int k = 0; k < NB; ++k) { sp += hp[k]; st += ht[k]; }

    float val = fabsf(hp[i] / (sp + 1e-7f) - ht[i] / (st + 1e-7f));

    #pragma unroll
    for (int off = 32; off > 0; off >>= 1)
        val += __shfl_down(val, off, 64);

    __shared__ float r[6];
    const int lane = t & 63, wv = t >> 6;
    if (lane == 0) r[wv] = val;
    __syncthreads();
    if (t == 0)
        out[0] = (r[0] + r[1] + r[2] + r[3] + r[4] + r[5]) * (1.0f / 384.0f);
}

extern "C" void kernel_launch(void* const* d_in, const int* in_sizes, int n_in,
                              void* d_out, int out_size, void* d_ws, size_t ws_size,
                              hipStream_t stream)
{
    const float* pred = (const float*)d_in[0];
    const float* tgt  = (const float*)d_in[1];

    unsigned int* partial = (unsigned int*)d_ws;  // 3*8*128*512*4 = 6.29 MB
    float* out2 = (float*)((char*)d_ws + (size_t)3 * BATCH * CHUNKS * FBINS * 4);

    count_kernel<<<dim3(CHUNKS, BATCH), CTHREADS, 0, stream>>>(pred, tgt, partial);
    combine_kernel<<<dim3(SLICES, 24), 512, 0, stream>>>(partial, out2);
    finalize_kernel<<<1, 384, 0, stream>>>(out2, (float*)d_out);
}